// Round 2
// baseline (110.135 us; speedup 1.0000x reference)
//
#include <hip/hip_runtime.h>

// ---------------------------------------------------------------------------
// Fused Sparse-MMoE forward for MI355X (gfx950).
// B=65536, D=512, E=8, H1=64, H2=32, O=64, T=2, K=2.
// One block = 64 tokens, 16 waves = 8 experts x 2 (N-split).
// Expert MLP: bf16 MFMA 16x16x32, all intermediates in LDS.
// Gating: exact fp32 VALU (register X chunks x SGPR-uniform weights),
//         so top-2 selection matches the fp32 reference.
// ---------------------------------------------------------------------------

typedef short bfrag __attribute__((ext_vector_type(8)));   // 8 bf16 = 4 VGPRs
typedef float facc  __attribute__((ext_vector_type(4)));   // 4 f32 accum

#define MFMA16(a, b, c) __builtin_amdgcn_mfma_f32_16x16x32_bf16((a), (b), (c), 0, 0, 0)

__device__ __forceinline__ unsigned short bfbits(float f) {
  unsigned int u = __builtin_bit_cast(unsigned int, f);
  u += 0x7FFFu + ((u >> 16) & 1u);          // RNE
  return (unsigned short)(u >> 16);
}
__device__ __forceinline__ float bf2f(unsigned short s) {
  unsigned int u = ((unsigned int)s) << 16;
  return __builtin_bit_cast(float, u);
}

// LDS map (bytes):
//  [0,      65536) : X tile [64][512] bf16 pitch 1024 (later aliased by H2 [8][64][32] pitch 64)
//  [65536, 131072) : gating partials [16w][64tok][16te] f32 (later H1/Out [8][64][64] bf16 pitch 128)
//  [131072,136192) : G logits [64][20] f32
//  [136192,136320) : imp/load partials [32] f32
#define H1_OFF 65536
#define G_OFF  131072
#define A_OFF  136192
#define SMEM_BYTES 136320

__global__ __launch_bounds__(1024) void moe_main(
    const float* __restrict__ x,
    const float* __restrict__ b_gates,
    const float* __restrict__ b1,
    const float* __restrict__ b2,
    const float* __restrict__ b3,
    const bfrag* __restrict__ w1f,
    const bfrag* __restrict__ w2f,
    const bfrag* __restrict__ w3f,
    const float* __restrict__ wgt,   // [16 te][512 k] f32 (te = t*8+e)
    float* __restrict__ gacc_out,
    float* __restrict__ y)
{
  __shared__ alignas(16) char smem[SMEM_BYTES];
  const int tid  = threadIdx.x;
  const int wave = tid >> 6, lane = tid & 63;
  const int q = lane & 15, g = lane >> 4;
  const int e = wave >> 1, h = wave & 1;

  // ------------- stage X (wave w = k-chunk [32w,32w+32), lane = token) -------------
  const float* xblk = x + (size_t)blockIdx.x * 64 * 512;
  const float* src = xblk + lane * 512 + wave * 32;
  float4 fr[8];
  #pragma unroll
  for (int j = 0; j < 8; ++j) fr[j] = ((const float4*)src)[j];

  // bf16 X tile -> LDS (swizzled, row = lane/token, cols wave*32 + j*4 ..)
  #pragma unroll
  for (int j = 0; j < 8; ++j) {
    unsigned int lo = (unsigned)bfbits(fr[j].x) | ((unsigned)bfbits(fr[j].y) << 16);
    unsigned int hi = (unsigned)bfbits(fr[j].z) | ((unsigned)bfbits(fr[j].w) << 16);
    unsigned byte = ((unsigned)(lane * 1024 + wave * 64 + j * 8)) ^ ((unsigned)(lane & 7) << 4);
    uint2 p; p.x = lo; p.y = hi;
    *(uint2*)(smem + byte) = p;
  }
  if (tid < 32) ((float*)(smem + A_OFF))[tid] = 0.f;

  // ------------- gating partial dots: exact fp32, wave-uniform weights -------------
  {
    int wu = __builtin_amdgcn_readfirstlane(wave);
    const float* wbase = wgt + wu * 32;
    float* pp = (float*)(smem + H1_OFF + wave * 4096 + lane * 64);
    #pragma unroll
    for (int te = 0; te < 16; ++te) {
      const float* wrow = wbase + te * 512;
      float a0 = 0.f, a1 = 0.f, a2 = 0.f, a3 = 0.f;
      #pragma unroll
      for (int j = 0; j < 8; ++j) {
        a0 = fmaf(fr[j].x, wrow[j * 4 + 0], a0);
        a1 = fmaf(fr[j].y, wrow[j * 4 + 1], a1);
        a2 = fmaf(fr[j].z, wrow[j * 4 + 2], a2);
        a3 = fmaf(fr[j].w, wrow[j * 4 + 3], a3);
      }
      pp[(te + lane) & 15] = (a0 + a1) + (a2 + a3);   // te-rotation: bank-conflict-free
    }
  }
  __syncthreads();

  // reduce partials across 16 waves -> G logits (f32) + bias
  {
    int tok = tid >> 4, te = tid & 15;
    const char* pb = smem + H1_OFF + tok * 64 + (((te + tok) & 15) * 4);
    float s = 0.f;
    #pragma unroll
    for (int w2 = 0; w2 < 16; ++w2) s += *(const float*)(pb + w2 * 4096);
    ((float*)(smem + G_OFF))[tok * 20 + te] = s + b_gates[te];
  }
  __syncthreads();

  // ---------------- GEMM1: H1 = relu(X @ W1[e] + b1), K=512 ----------------
  facc acc1[4][2];
  #pragma unroll
  for (int m = 0; m < 4; ++m) { acc1[m][0] = (facc)0.f; acc1[m][1] = (facc)0.f; }

  const bfrag* w1e = w1f + (size_t)e * 4096 + (size_t)(2 * h) * 64 + lane;
  #pragma unroll
  for (int ks = 0; ks < 16; ++ks) {
    bfrag bb0 = w1e[ks * 256];
    bfrag bb1 = w1e[ks * 256 + 64];
    #pragma unroll
    for (int m = 0; m < 4; ++m) {
      int r = m * 16 + q;
      unsigned byte = ((unsigned)(r * 1024 + ks * 64 + g * 16)) ^ ((unsigned)(r & 7) << 4);
      bfrag a = *(const bfrag*)(smem + byte);
      acc1[m][0] = MFMA16(a, bb0, acc1[m][0]);
      acc1[m][1] = MFMA16(a, bb1, acc1[m][1]);
    }
  }

  // H1 -> LDS (bf16, sigma-packed: storage col s = q*4 + nt)
  {
    float bv0 = b1[e * 64 + (2 * h) * 16 + q];
    float bv1 = b1[e * 64 + (2 * h + 1) * 16 + q];
    char* h1b = smem + H1_OFF + e * 8192;
    #pragma unroll
    for (int m = 0; m < 4; ++m) {
      #pragma unroll
      for (int j = 0; j < 4; ++j) {
        float v0 = fmaxf(acc1[m][0][j] + bv0, 0.f);
        float v1 = fmaxf(acc1[m][1][j] + bv1, 0.f);
        int r = m * 16 + g * 4 + j;
        unsigned byte = ((unsigned)(r * 128 + (q * 4 + 2 * h) * 2)) ^ ((unsigned)(r & 7) << 4);
        *(unsigned int*)(h1b + byte) = (unsigned)bfbits(v0) | ((unsigned)bfbits(v1) << 16);
      }
    }
  }
  __syncthreads();

  // ---------------- GEMM2: H2 = relu(H1 @ W2[e] + b2), K=64 ----------------
  {
    facc acc2[4];
    #pragma unroll
    for (int m = 0; m < 4; ++m) acc2[m] = (facc)0.f;
    const char* h1b = smem + H1_OFF + e * 8192;
    #pragma unroll
    for (int ks = 0; ks < 2; ++ks) {
      bfrag bb = w2f[((e * 2 + ks) * 2 + h) * 64 + lane];
      #pragma unroll
      for (int m = 0; m < 4; ++m) {
        int r = m * 16 + q;
        unsigned byte = ((unsigned)(r * 128 + ks * 64 + g * 16)) ^ ((unsigned)(r & 7) << 4);
        bfrag a = *(const bfrag*)(h1b + byte);
        acc2[m] = MFMA16(a, bb, acc2[m]);
      }
    }
    float bv = b2[e * 32 + h * 16 + q];
    char* h2b = smem + e * 4096;   // aliases X region (dead)
    #pragma unroll
    for (int m = 0; m < 4; ++m) {
      #pragma unroll
      for (int j = 0; j < 4; ++j) {
        float v = fmaxf(acc2[m][j] + bv, 0.f);
        int r = m * 16 + g * 4 + j;
        unsigned byte = ((unsigned)(r * 64 + (q * 2 + h) * 2)) ^ ((unsigned)(r & 7) << 4);
        *(unsigned short*)(h2b + byte) = bfbits(v);
      }
    }
  }
  __syncthreads();

  // ---------------- GEMM3: Out = relu(H2 @ W3[e] + b3), K=32 ----------------
  {
    facc acc3[4][2];
    #pragma unroll
    for (int m = 0; m < 4; ++m) { acc3[m][0] = (facc)0.f; acc3[m][1] = (facc)0.f; }
    const char* h2b = smem + e * 4096;
    bfrag c0 = w3f[(e * 4 + 2 * h) * 64 + lane];
    bfrag c1 = w3f[(e * 4 + 2 * h + 1) * 64 + lane];
    #pragma unroll
    for (int m = 0; m < 4; ++m) {
      int r = m * 16 + q;
      unsigned byte = ((unsigned)(r * 64 + g * 16)) ^ ((unsigned)(r & 7) << 4);
      bfrag a = *(const bfrag*)(h2b + byte);
      acc3[m][0] = MFMA16(a, c0, acc3[m][0]);
      acc3[m][1] = MFMA16(a, c1, acc3[m][1]);
    }
    float bo0 = b3[e * 64 + (2 * h) * 16 + q];
    float bo1 = b3[e * 64 + (2 * h + 1) * 16 + q];
    char* ob = smem + H1_OFF + e * 8192;   // aliases H1 region (dead)
    #pragma unroll
    for (int m = 0; m < 4; ++m) {
      #pragma unroll
      for (int j = 0; j < 4; ++j) {
        float v0 = fmaxf(acc3[m][0][j] + bo0, 0.f);
        float v1 = fmaxf(acc3[m][1][j] + bo1, 0.f);
        int r = m * 16 + g * 4 + j;
        unsigned byte = ((unsigned)(r * 128 + (q * 4 + 2 * h) * 2)) ^ ((unsigned)(r & 7) << 4);
        *(unsigned int*)(ob + byte) = (unsigned)bfbits(v0) | ((unsigned)bfbits(v1) << 16);
      }
    }
  }
  __syncthreads();

  // ---------------- combine: top-2 softmax gating + weighted sum ----------------
  {
    int tok = tid >> 4, u = tid & 15;
    const float* G = (const float*)(smem + G_OFF) + tok * 20;
    float l[16];
    *(float4*)(l + 0)  = *(const float4*)(G + 0);
    *(float4*)(l + 4)  = *(const float4*)(G + 4);
    *(float4*)(l + 8)  = *(const float4*)(G + 8);
    *(float4*)(l + 12) = *(const float4*)(G + 12);
    float* lacc = (float*)(smem + A_OFF);
    size_t ybase_tok = (size_t)((size_t)blockIdx.x * 64 + tok) * 64;
    unsigned obyte = ((unsigned)(tok * 128 + u * 8)) ^ ((unsigned)(tok & 7) << 4);

    #pragma unroll
    for (int tt = 0; tt < 2; ++tt) {
      int base = tt * 8;
      float v1 = l[base]; int e1 = 0;
      #pragma unroll
      for (int ee = 1; ee < 8; ++ee) { float vv = l[base + ee]; if (vv > v1) { v1 = vv; e1 = ee; } }
      float v2 = -3.4e38f; int e2 = 0;
      #pragma unroll
      for (int ee = 0; ee < 8; ++ee) {
        float vv = l[base + ee];
        if (ee != e1 && vv > v2) { v2 = vv; e2 = ee; }
      }
      float g1 = 1.f / (1.f + __expf(v2 - v1));
      float g2 = 1.f - g1;

      uint2 o1 = *(const uint2*)(smem + H1_OFF + e1 * 8192 + obyte);
      uint2 o2 = *(const uint2*)(smem + H1_OFF + e2 * 8192 + obyte);
      unsigned short s1[4] = { (unsigned short)o1.x, (unsigned short)(o1.x >> 16),
                               (unsigned short)o1.y, (unsigned short)(o1.y >> 16) };
      unsigned short s2[4] = { (unsigned short)o2.x, (unsigned short)(o2.x >> 16),
                               (unsigned short)o2.y, (unsigned short)(o2.y >> 16) };
      float* yt = y + (size_t)tt * 4194304 + ybase_tok;
      #pragma unroll
      for (int w = 0; w < 4; ++w) {
        // storage col s = 4u+w  ->  actual col c = w*16 + u
        yt[w * 16 + u] = g1 * bf2f(s1[w]) + g2 * bf2f(s2[w]);
      }
      if (u == 0) {
        atomicAdd(lacc + tt * 8 + e1, g1);
        atomicAdd(lacc + tt * 8 + e2, g2);
        atomicAdd(lacc + 16 + tt * 8 + e1, 1.f);
        atomicAdd(lacc + 16 + tt * 8 + e2, 1.f);
      }
    }
  }
  __syncthreads();
  if (tid < 32) atomicAdd(gacc_out + tid, ((float*)(smem + A_OFF))[tid]);
}

// ---------------------------------------------------------------------------
// Weight repack: expert weights fp32 -> bf16 MFMA B-fragment order; gate
// weights fp32 -> transposed [te][k] fp32 (exact, for fp32 gating).
//  w1f: [E][16ks][4nt][64lane][8]    B = W1[k][h], h = nt*16+q
//  w2f: [E][2ks][2nt][64][8]         K in H1-storage order: h = (s&3)*16 + (s>>2)
//  w3f: [E][1][4nt][64][8]           K in H2-storage order: h = (s&1)*16 + (s>>1)
//  wgt: [16 te][512 k] f32           te = t*8+e
// ---------------------------------------------------------------------------
__global__ __launch_bounds__(256) void moe_prep(
    const float* __restrict__ W1, const float* __restrict__ W2,
    const float* __restrict__ W3, const float* __restrict__ wg,
    bfrag* __restrict__ w1f, bfrag* __restrict__ w2f,
    bfrag* __restrict__ w3f, float* __restrict__ wgt)
{
  int tid = blockIdx.x * 256 + threadIdx.x;
  bfrag o;
  if (tid < 32768) {
    int lane = tid & 63, nt = (tid >> 6) & 3, ks = (tid >> 8) & 15, e = tid >> 12;
    int q = lane & 15, g = lane >> 4;
    int hcol = nt * 16 + q;
    #pragma unroll
    for (int j = 0; j < 8; ++j) {
      int k = ks * 32 + g * 8 + j;
      o[j] = (short)bfbits(W1[((e * 512 + k) * 64) + hcol]);
    }
    w1f[tid] = o;
  } else if (tid < 34816) {
    int idx = tid - 32768;
    int lane = idx & 63, nt = (idx >> 6) & 1, ks = (idx >> 7) & 1, e = idx >> 8;
    int q = lane & 15, g = lane >> 4;
    int n = nt * 16 + q;
    #pragma unroll
    for (int j = 0; j < 8; ++j) {
      int s = ks * 32 + g * 8 + j;
      int hh = (s & 3) * 16 + (s >> 2);
      o[j] = (short)bfbits(W2[(e * 64 + hh) * 32 + n]);
    }
    w2f[idx] = o;
  } else if (tid < 36864) {
    int idx = tid - 34816;
    int lane = idx & 63, nt = (idx >> 6) & 3, e = idx >> 8;
    int q = lane & 15, g = lane >> 4;
    int ocol = nt * 16 + q;
    #pragma unroll
    for (int j = 0; j < 8; ++j) {
      int s = g * 8 + j;
      int hh = (s & 1) * 16 + (s >> 1);
      o[j] = (short)bfbits(W3[(e * 32 + hh) * 64 + ocol]);
    }
    w3f[idx] = o;
  } else if (tid < 45056) {
    int idx = tid - 36864;            // [0, 8192): te = idx>>9, k = idx&511
    int te = idx >> 9, k = idx & 511;
    wgt[idx] = wg[(((te >> 3) * 512) + k) * 8 + (te & 7)];   // exact f32 copy
  }
}

// loss = 0.01 * sum_t [ cv(importance_t) + cv(load_t) ],  cv = var(ddof=1)/(mean^2+1e-10)
__global__ void moe_loss(const float* __restrict__ acc, float* __restrict__ out) {
  if (threadIdx.x == 0 && blockIdx.x == 0) {
    float loss = 0.f;
    for (int a = 0; a < 4; ++a) {        // [imp t0][imp t1][load t0][load t1]
      const float* v = acc + a * 8;
      float m = 0.f;
      for (int i = 0; i < 8; ++i) m += v[i];
      m *= 0.125f;
      float var = 0.f;
      for (int i = 0; i < 8; ++i) { float d = v[i] - m; var += d * d; }
      var *= (1.f / 7.f);
      loss += var / (m * m + 1e-10f);
    }
    out[8388608] = 0.01f * loss;
  }
}

extern "C" void kernel_launch(void* const* d_in, const int* in_sizes, int n_in,
                              void* d_out, int out_size, void* d_ws, size_t ws_size,
                              hipStream_t stream) {
  const float* x  = (const float*)d_in[0];
  const float* wg = (const float*)d_in[1];
  const float* bg = (const float*)d_in[2];
  const float* W1 = (const float*)d_in[3];
  const float* b1 = (const float*)d_in[4];
  const float* W2 = (const float*)d_in[5];
  const float* b2 = (const float*)d_in[6];
  const float* W3 = (const float*)d_in[7];
  const float* b3 = (const float*)d_in[8];
  float* y = (float*)d_out;

  char* ws = (char*)d_ws;
  float* gacc = (float*)ws;                    // [32] f32 accumulators
  bfrag* w1f = (bfrag*)(ws + 128);             // 524288 B
  bfrag* w2f = (bfrag*)(ws + 524416);          // 32768 B
  bfrag* w3f = (bfrag*)(ws + 557184);          // 32768 B
  float* wgt = (float*)(ws + 589952);          // 32768 B f32

  hipMemsetAsync(gacc, 0, 128, stream);
  moe_prep<<<176, 256, 0, stream>>>(W1, W2, W3, wg, w1f, w2f, w3f, wgt);
  moe_main<<<1024, 1024, 0, stream>>>(x, bg, b1, b2, b3, w1f, w2f, w3f, wgt, gacc, y);
  moe_loss<<<1, 64, 0, stream>>>(gacc, y);
}